// Round 10
// baseline (364.100 us; speedup 1.0000x reference)
//
#include <hip/hip_runtime.h>
#include <hip/hip_fp16.h>
#include <math.h>

#define N_NODES 100000
#define N_BASE  5000
#define N_EDGES 3200000
#define NBKT    391       // dest buckets of 256 nodes
#define CAPB    9472      // csr slots per bucket (mean 8184, sigma 90 -> +14 sigma)
#define EPB     2048      // edges per k_bucket block (round 10: fits 6 blocks/CU)
#define EPT     4         // edges per thread (512 threads)
#define GEB     1563      // ceil(N_EDGES / EPB)

__device__ inline unsigned pkh(float a, float b) {
    return (unsigned)__half_as_ushort(__float2half_rn(a)) |
           ((unsigned)__half_as_ushort(__float2half_rn(b)) << 16);
}

__device__ inline unsigned hadd2u(unsigned a, unsigned b) {
    __half2 r = __hadd2(*(__half2*)&a, *(__half2*)&b);
    return *(unsigned*)&r;
}

// ---------------------------------------------------------------------------
// k_initg: gcur[b] = b*CAPB, bins = 0
// ---------------------------------------------------------------------------
__global__ __launch_bounds__(512) void k_initg(int* __restrict__ gcur, float* __restrict__ bins) {
    int t = threadIdx.x;
    if (t < NBKT) gcur[t] = t * CAPB;
    if (t < 64) bins[t] = 0.0f;
}

// ---------------------------------------------------------------------------
// k_bucket (round 10): single-pass register staging. Each thread holds its
// EPT=4 edges (col,row) in registers from the ONE global read; the position
// pass reads registers, not global (removes a full dependent global round).
// EPB 2048 -> LDS ~24.3KB -> 6 blocks/CU (was 3 at 41.5KB, occupancy 36%).
// Run-linear global writes kept (round-5 verified).
// ---------------------------------------------------------------------------
__global__ __launch_bounds__(512) void k_bucket(const int* __restrict__ row, const int* __restrict__ col,
                                                int* __restrict__ gcur, unsigned* __restrict__ csr) {
    __shared__ int hist[NBKT], gbase[NBKT], curi[NBKT], excl[NBKT];
    __shared__ int sc[512];
    __shared__ unsigned sdst[EPB];     // packed (d&255)<<17 | src, sorted by bucket
    __shared__ int sadr[EPB];          // final global csr address per slot
    int t = threadIdx.x;
    int e0 = blockIdx.x * EPB;
    int cnt = (N_EDGES - e0 < EPB) ? (N_EDGES - e0) : EPB;
    int dj[EPT], sj[EPT];
    bool vj[EPT];
    for (int k = t; k < NBKT; k += 512) hist[k] = 0;
#pragma unroll
    for (int i = 0; i < EPT; i++) {
        int j = t + i * 512;
        vj[i] = j < cnt;
        int jj = vj[i] ? j : 0;
        dj[i] = col[e0 + jj];
        sj[i] = row[e0 + jj];
    }
    __syncthreads();
#pragma unroll
    for (int i = 0; i < EPT; i++) if (vj[i]) atomicAdd(&hist[dj[i] >> 8], 1);
    __syncthreads();
    sc[t] = (t < NBKT) ? hist[t] : 0;
    __syncthreads();
    for (int off = 1; off < 512; off <<= 1) {
        int v = (t >= off) ? sc[t - off] : 0;
        __syncthreads();
        sc[t] += v;
        __syncthreads();
    }
    if (t < NBKT) {
        int e = sc[t] - hist[t];
        excl[t] = e;
        curi[t] = e;
        gbase[t] = (hist[t] > 0) ? atomicAdd(&gcur[t], hist[t]) : 0;
    }
    __syncthreads();
#pragma unroll
    for (int i = 0; i < EPT; i++) if (vj[i]) {
        int b = dj[i] >> 8;
        int pos = atomicAdd(&curi[b], 1);              // pos in [excl[b], excl[b]+hist[b])
        sdst[pos] = ((unsigned)(dj[i] & 255) << 17) | (unsigned)sj[i];
        sadr[pos] = gbase[b] + (pos - excl[b]);
    }
    __syncthreads();
    for (int j = t; j < cnt; j += 512) csr[sadr[j]] = sdst[j];   // run-linear writes
}

// ---------------------------------------------------------------------------
// k_sort: one block per bucket, 1024 threads; LDS counting sort (verified).
// ---------------------------------------------------------------------------
__global__ __launch_bounds__(1024) void k_sort(const int* __restrict__ gcur, unsigned* __restrict__ csr,
                                               int* __restrict__ rs, int* __restrict__ re,
                                               float* __restrict__ dinv) {
    __shared__ unsigned stage[CAPB];
    __shared__ int hist[256], offs[256], cur[256];
    int t = threadIdx.x, b = blockIdx.x;
    int base = b * CAPB;
    int cnt = gcur[b] - base;
    if (t < 256) hist[t] = 0;
    for (int j = t; j < cnt; j += 1024) stage[j] = csr[base + j];
    __syncthreads();
    for (int j = t; j < cnt; j += 1024) atomicAdd(&hist[stage[j] >> 17], 1);
    __syncthreads();
    if (t < 256) offs[t] = hist[t];
    __syncthreads();
    for (int off = 1; off < 256; off <<= 1) {
        int v = 0;
        if (t < 256 && t >= off) v = offs[t - off];
        __syncthreads();
        if (t < 256) offs[t] += v;
        __syncthreads();
    }
    if (t < 256) {
        int excl = offs[t] - hist[t];
        cur[t] = excl;
        int node = b * 256 + t;
        if (node < N_NODES) {
            rs[node] = base + excl;
            re[node] = base + excl + hist[t];
            dinv[node] = rsqrtf((float)(hist[t] + 1));   // +1 self loop
        }
    }
    __syncthreads();
    for (int j = t; j < cnt; j += 1024) {
        unsigned p = stage[j];
        int slot = atomicAdd(&cur[p >> 17], 1);
        csr[base + slot] = p & 0x1FFFFu;             // pure src
    }
}

// ---------------------------------------------------------------------------
// k_ab_h: bb = [x1 | tile(x2)] @ W4^T + b4  (float4 stores, f32)
//         h0 = dinv * (Wg @ [relu(x1@W1^T+b1) | bb])   (fp16 stores)
//         bins += W3[15:34].bb   (iteration-invariant output part)
// ---------------------------------------------------------------------------
__global__ __launch_bounds__(256) void k_ab_h(const float* __restrict__ x1, const float* __restrict__ x2,
                                              const float* __restrict__ W1, const float* __restrict__ b1,
                                              const float* __restrict__ W4, const float* __restrict__ b4,
                                              const float* __restrict__ Wg, const float* __restrict__ W3,
                                              const float* __restrict__ dinv,
                                              float* __restrict__ bb, __half* __restrict__ h0,
                                              float* __restrict__ bins) {
    __shared__ float sW1[225], sb1[15], sW4[361], sb4[19], sWg[510], sW3b[19];
    for (int t = threadIdx.x; t < 225; t += 256) sW1[t] = W1[t];
    for (int t = threadIdx.x; t < 361; t += 256) sW4[t] = W4[t];
    for (int t = threadIdx.x; t < 510; t += 256) sWg[t] = Wg[t];
    if (threadIdx.x < 15) sb1[threadIdx.x] = b1[threadIdx.x];
    if (threadIdx.x < 19) { sb4[threadIdx.x] = b4[threadIdx.x]; sW3b[threadIdx.x] = W3[15 + threadIdx.x]; }
    __syncthreads();
    int i = blockIdx.x * 256 + threadIdx.x;
    bool valid = i < N_NODES;
    int ii = valid ? i : 0;
    float x[15];
#pragma unroll
    for (int k = 0; k < 15; k++) x[k] = x1[(size_t)ii * 15 + k];
    float xt[4];
    int ib = ii % N_BASE;
#pragma unroll
    for (int k = 0; k < 4; k++) xt[k] = x2[(size_t)ib * 4 + k];
    float in[34];
    float bp = 0.0f;
#pragma unroll
    for (int o = 0; o < 19; o++) {
        float s = sb4[o];
#pragma unroll
        for (int k = 0; k < 15; k++) s += x[k] * sW4[o * 19 + k];
#pragma unroll
        for (int k = 0; k < 4; k++) s += xt[k] * sW4[o * 19 + 15 + k];
        in[15 + o] = s;
        bp += s * sW3b[o];
    }
#pragma unroll
    for (int o = 0; o < 15; o++) {
        float s = sb1[o];
#pragma unroll
        for (int k = 0; k < 15; k++) s += x[k] * sW1[o * 15 + k];
        in[o] = fmaxf(s, 0.0f);
    }
    float dn = dinv[ii];
    if (valid) {
        float4* bbp = (float4*)(bb + (size_t)ii * 20);
        bbp[0] = make_float4(in[15], in[16], in[17], in[18]);
        bbp[1] = make_float4(in[19], in[20], in[21], in[22]);
        bbp[2] = make_float4(in[23], in[24], in[25], in[26]);
        bbp[3] = make_float4(in[27], in[28], in[29], in[30]);
        bbp[4] = make_float4(in[31], in[32], in[33], 0.0f);   // [19] pad, never consumed
        float hv[15];
#pragma unroll
        for (int o = 0; o < 15; o++) {
            float s = 0.0f;
#pragma unroll
            for (int k = 0; k < 34; k++) s += in[k] * sWg[o * 34 + k];
            hv[o] = s * dn;
        }
        unsigned hu[8];
#pragma unroll
        for (int k = 0; k < 7; k++) hu[k] = pkh(hv[2 * k], hv[2 * k + 1]);
        hu[7] = pkh(hv[14], 0.0f);                            // ch 15 pad, always 0
        uint4* hp = (uint4*)(h0 + (size_t)ii * 16);
        hp[0] = make_uint4(hu[0], hu[1], hu[2], hu[3]);
        hp[1] = make_uint4(hu[4], hu[5], hu[6], hu[7]);
    }
    float val = valid ? bp : 0.0f;
#pragma unroll
    for (int off = 32; off > 0; off >>= 1) val += __shfl_down(val, off, 64);
    __shared__ float wsum[4];
    if ((threadIdx.x & 63) == 0) wsum[threadIdx.x >> 6] = val;
    __syncthreads();
    if (threadIdx.x == 0) atomicAdd(&bins[blockIdx.x & 63], wsum[0] + wsum[1] + wsum[2] + wsum[3]);
}

// ---------------------------------------------------------------------------
// k_gather (round 10): identical wave-level algorithm to round 9 (verified),
// but 256-thread blocks (4 waves, 8 nodes) instead of 1024. Rationale: VGPR
// 24 / LDS 2.5KB cap nothing -- the 16-wave block quantum was the occupancy
// limiter (58%). 256-thread blocks allow 8 blocks/CU = 32 waves = 100%.
// ---------------------------------------------------------------------------
__global__ __launch_bounds__(256) void k_gather(const int* __restrict__ rs, const int* __restrict__ re,
                                                const unsigned* __restrict__ csr,
                                                const __half* __restrict__ h_in,
                                                const float* __restrict__ dinv,
                                                const float* __restrict__ bb,
                                                const float* __restrict__ Wg,
                                                const float* __restrict__ bg,
                                                const float* __restrict__ W3,
                                                __half* __restrict__ h_out,
                                                float* __restrict__ bins, int last) {
    __shared__ float sWg[544], sbg[16], sW3[16];
    __shared__ float ws2[4];
    int t = threadIdx.x;
    for (int k = t; k < 544; k += 256) sWg[k] = (k < 510) ? Wg[k] : 0.0f;
    if (t < 16) { sbg[t] = (t < 15) ? bg[t] : 0.0f; sW3[t] = (t < 15) ? W3[t] : 0.0f; }
    __syncthreads();
    int wid = t >> 6;
    int n0 = blockIdx.x * 8 + wid * 2;
    int lane = t & 63, g = lane >> 5, lg = lane & 31;
    int ng = n0 + g;
    int rsg = rs[ng];
    int degg = re[ng] - rsg;
    int dego = __shfl_xor(degg, 32, 64);
    int degm = degg > dego ? degg : dego;                  // wave-uniform bound
    const uint4* hp4 = (const uint4*)h_in;                 // one row = 2 uint4 (32B)
    // self row: full row on the lg==0 lane of each group (counted exactly once)
    uint4 sL = make_uint4(0u, 0u, 0u, 0u), sH = make_uint4(0u, 0u, 0u, 0u);
    if (lg == 0) { sL = hp4[(size_t)ng * 2]; sH = hp4[(size_t)ng * 2 + 1]; }
    unsigned a0 = sL.x, a1 = sL.y, a2 = sL.z, a3 = sL.w;
    unsigned a4 = sH.x, a5 = sH.y, a6 = sH.z, a7 = sH.w;
    for (int base = 0; base < degm; base += 64) {
        bool vA = base + lg < degg;
        bool vB = base + 32 + lg < degg;
        unsigned pa = 0u, pb = 0u;
        if (vA) pa = csr[rsg + base + lg];
        if (vB) pb = csr[rsg + base + 32 + lg];
        uint4 vaL = make_uint4(0u, 0u, 0u, 0u), vaH = make_uint4(0u, 0u, 0u, 0u);
        uint4 vbL = make_uint4(0u, 0u, 0u, 0u), vbH = make_uint4(0u, 0u, 0u, 0u);
        if (vA) { vaL = hp4[(size_t)pa * 2]; vaH = hp4[(size_t)pa * 2 + 1]; }
        if (vB) { vbL = hp4[(size_t)pb * 2]; vbH = hp4[(size_t)pb * 2 + 1]; }
        a0 = hadd2u(a0, vaL.x); a1 = hadd2u(a1, vaL.y);
        a2 = hadd2u(a2, vaL.z); a3 = hadd2u(a3, vaL.w);
        a4 = hadd2u(a4, vaH.x); a5 = hadd2u(a5, vaH.y);
        a6 = hadd2u(a6, vaH.z); a7 = hadd2u(a7, vaH.w);
        a0 = hadd2u(a0, vbL.x); a1 = hadd2u(a1, vbL.y);
        a2 = hadd2u(a2, vbL.z); a3 = hadd2u(a3, vbL.w);
        a4 = hadd2u(a4, vbH.x); a5 = hadd2u(a5, vbH.y);
        a6 = hadd2u(a6, vbH.z); a7 = hadd2u(a7, vbH.w);
    }
    // per-lane reduce over lg bits 0..4 (send-the-discard-half); lane ends
    // holding row dword pr = 4*b0 + 2*b1 + b2 of its node's sum.
    int b0 = lg & 1, b1 = (lg >> 1) & 1, b2 = (lg >> 2) & 1;
    unsigned kA0 = b0 ? a4 : a0, kA1 = b0 ? a5 : a1, kA2 = b0 ? a6 : a2, kA3 = b0 ? a7 : a3;
    unsigned sA0 = b0 ? a0 : a4, sA1 = b0 ? a1 : a5, sA2 = b0 ? a2 : a6, sA3 = b0 ? a3 : a7;
    kA0 = hadd2u(kA0, __shfl_xor(sA0, 1, 64));
    kA1 = hadd2u(kA1, __shfl_xor(sA1, 1, 64));
    kA2 = hadd2u(kA2, __shfl_xor(sA2, 1, 64));
    kA3 = hadd2u(kA3, __shfl_xor(sA3, 1, 64));
    unsigned kB0 = b1 ? kA2 : kA0, kB1 = b1 ? kA3 : kA1;
    unsigned sB0 = b1 ? kA0 : kA2, sB1 = b1 ? kA1 : kA3;
    kB0 = hadd2u(kB0, __shfl_xor(sB0, 2, 64));
    kB1 = hadd2u(kB1, __shfl_xor(sB1, 2, 64));
    unsigned kk = b2 ? kB1 : kB0;
    unsigned sd = b2 ? kB0 : kB1;
    kk = hadd2u(kk, __shfl_xor(sd, 4, 64));
    kk = hadd2u(kk, __shfl_xor(kk, 8, 64));
    kk = hadd2u(kk, __shfl_xor(kk, 16, 64));
    int pr = 4 * b0 + 2 * b1 + b2;
    float dng = dinv[ng];
    float2 f = __half22float2(*(__half2*)&kk);
    float avx = fmaxf(dng * f.x + sbg[2 * pr], 0.0f);
    float avy = fmaxf(dng * f.y + sbg[2 * pr + 1], 0.0f);   // pr==7 -> ch15 = 0
    if (!last) {
        int n1 = n0 + 1;
        float dn0 = __shfl(dng, 0, 64), dn1 = __shfl(dng, 32, 64);
        int p = lane >> 3, c2e = lane & 7, o0 = 2 * c2e;
        // pair j of node g lives on lane 32*g + rev3(j)
        int j0 = p >> 1, j1 = (p + 8) >> 1;
        int l0 = ((j0 & 1) << 2) | (j0 & 2) | ((j0 >> 2) & 1);
        int l1 = ((j1 & 1) << 2) | (j1 & 2) | ((j1 >> 2) & 1);
        float ex0a = __shfl(avx, l0, 64),      ey0a = __shfl(avy, l0, 64);
        float ex1a = __shfl(avx, l1, 64),      ey1a = __shfl(avy, l1, 64);
        float ex0b = __shfl(avx, 32 + l0, 64), ey0b = __shfl(avy, 32 + l0, 64);
        float ex1b = __shfl(avx, 32 + l1, 64), ey1b = __shfl(avy, 32 + l1, 64);
        float inv0a = (p & 1) ? ey0a : ex0a;
        float inv1a = (p & 1) ? ey1a : ex1a;
        float inv0b = (p & 1) ? ey0b : ex0b;
        float inv1b = (p & 1) ? ey1b : ex1b;
        if (p == 7) { inv1a = bb[(size_t)n0 * 20 + 0]; inv1b = bb[(size_t)n1 * 20 + 0]; }
        float wq0 = sWg[o0 * 34 + p],       wq1 = sWg[o0 * 34 + p + 8];
        float wr0 = sWg[(o0 + 1) * 34 + p], wr1 = sWg[(o0 + 1) * 34 + p + 8];
        float s0a = inv0a * wq0 + inv1a * wq1;
        float s1a = inv0a * wr0 + inv1a * wr1;
        float s0b = inv0b * wq0 + inv1b * wq1;
        float s1b = inv0b * wr0 + inv1b * wr1;
#pragma unroll
        for (int i = 2; i < 5; i++) {
            int k = p + 8 * i;
            if (k < 34) {
                float ia = bb[(size_t)n0 * 20 + (k - 15)];
                float ib2 = bb[(size_t)n1 * 20 + (k - 15)];
                float w0 = sWg[o0 * 34 + k], w1 = sWg[(o0 + 1) * 34 + k];
                s0a += ia * w0; s1a += ia * w1;
                s0b += ib2 * w0; s1b += ib2 * w1;
            }
        }
        s0a += __shfl_xor(s0a, 8, 64);  s1a += __shfl_xor(s1a, 8, 64);
        s0a += __shfl_xor(s0a, 16, 64); s1a += __shfl_xor(s1a, 16, 64);
        s0a += __shfl_xor(s0a, 32, 64); s1a += __shfl_xor(s1a, 32, 64);
        s0b += __shfl_xor(s0b, 8, 64);  s1b += __shfl_xor(s1b, 8, 64);
        s0b += __shfl_xor(s0b, 16, 64); s1b += __shfl_xor(s1b, 16, 64);
        s0b += __shfl_xor(s0b, 32, 64); s1b += __shfl_xor(s1b, 32, 64);
        if (p == 0) {
            ((unsigned*)h_out)[(size_t)n0 * 8 + c2e] = pkh(s0a * dn0, s1a * dn0);
            ((unsigned*)h_out)[(size_t)n1 * 8 + c2e] = pkh(s0b * dn1, s1b * dn1);
        }
    } else {
        float c = 0.0f;
        if (lg < 8) c = avx * sW3[2 * pr] + avy * sW3[2 * pr + 1];   // sW3[15]==0
        c += __shfl_xor(c, 1, 64);
        c += __shfl_xor(c, 2, 64);
        c += __shfl_xor(c, 4, 64);        // lane0 = node0 sum, lane32 = node1 sum
        c += __shfl_xor(c, 32, 64);       // combine groups
        if (lane == 0) ws2[wid] = c;
        __syncthreads();
        if (t == 0) {
            float s = ws2[0] + ws2[1] + ws2[2] + ws2[3];
            atomicAdd(&bins[blockIdx.x & 63], s);
        }
    }
}

__global__ void k_finalize(const float* __restrict__ bins, const float* __restrict__ b3,
                           float* __restrict__ out) {
    float s = 0.0f;
    for (int k = 0; k < 64; k++) s += bins[k];
    out[0] = tanhf(s * (1.0f / (float)N_NODES) + b3[0]);
}

// ---------------------------------------------------------------------------
extern "C" void kernel_launch(void* const* d_in, const int* in_sizes, int n_in,
                              void* d_out, int out_size, void* d_ws, size_t ws_size,
                              hipStream_t stream) {
    const float* x1 = (const float*)d_in[0];
    const float* x2 = (const float*)d_in[1];
    const int* edges = (const int*)d_in[2];
    const float* W1 = (const float*)d_in[3];
    const float* b1 = (const float*)d_in[4];
    const float* Wg = (const float*)d_in[5];
    const float* bg = (const float*)d_in[6];
    const float* W3 = (const float*)d_in[7];
    const float* b3 = (const float*)d_in[8];
    const float* W4 = (const float*)d_in[9];
    const float* b4 = (const float*)d_in[10];

    const int* row = edges;             // edges[0]
    const int* col = edges + N_EDGES;   // edges[1]

    // workspace layout — ~30 MB (h0/h1 fp16: 3.2 MB each).
    char* ws = (char*)d_ws;
    unsigned* csr  = (unsigned*)ws;                              // NBKT*CAPB  (14.81 MB)
    float*    bb   = (float*)(csr + (size_t)NBKT * CAPB);        // N*20 f32   (8.0 MB)
    __half*   h0   = (__half*)(bb + (size_t)N_NODES * 20);       // N*16 fp16  (3.2 MB)
    __half*   h1   = h0 + (size_t)N_NODES * 16;                  // N*16 fp16  (3.2 MB)
    float*    dinv = (float*)(h1 + (size_t)N_NODES * 16);        // N
    int*      rs   = (int*)(dinv + N_NODES);                     // N
    int*      re   = rs + N_NODES;                               // N
    int*      gcur = re + N_NODES;                               // NBKT
    float*    bins = (float*)(gcur + NBKT);                      // 64

    int gN = (N_NODES + 255) / 256;                              // 391

    k_initg<<<1, 512, 0, stream>>>(gcur, bins);
    k_bucket<<<GEB, 512, 0, stream>>>(row, col, gcur, csr);
    k_sort<<<NBKT, 1024, 0, stream>>>(gcur, csr, rs, re, dinv);
    k_ab_h<<<gN, 256, 0, stream>>>(x1, x2, W1, b1, W4, b4, Wg, W3, dinv, bb, h0, bins);
    for (int t = 0; t < 5; t++) {
        const __half* hi = (t & 1) ? h1 : h0;
        __half* ho = (t & 1) ? h0 : h1;
        k_gather<<<N_NODES / 8, 256, 0, stream>>>(rs, re, csr, hi, dinv, bb, Wg, bg, W3,
                                                  ho, bins, t == 4 ? 1 : 0);
    }
    k_finalize<<<1, 1, 0, stream>>>(bins, b3, (float*)d_out);
}

// Round 11
// 350.914 us; speedup vs baseline: 1.0376x; 1.0376x over previous
//
#include <hip/hip_runtime.h>
#include <hip/hip_fp16.h>
#include <math.h>

#define N_NODES 100000
#define N_BASE  5000
#define N_EDGES 3200000
#define NBKT    391       // dest buckets of 256 nodes
#define CAPB    9472      // csr slots per bucket (mean 8184, sigma 90 -> +14 sigma)
#define EPB     2048      // edges per k_bucket block (fits 6 blocks/CU)
#define EPT     4         // edges per thread (512 threads)
#define GEB     1563      // ceil(N_EDGES / EPB)

__device__ inline unsigned pkh(float a, float b) {
    return (unsigned)__half_as_ushort(__float2half_rn(a)) |
           ((unsigned)__half_as_ushort(__float2half_rn(b)) << 16);
}

__device__ inline unsigned hadd2u(unsigned a, unsigned b) {
    __half2 r = __hadd2(*(__half2*)&a, *(__half2*)&b);
    return *(unsigned*)&r;
}

// ---------------------------------------------------------------------------
// k_initg: gcur[b] = b*CAPB, bins = 0
// ---------------------------------------------------------------------------
__global__ __launch_bounds__(512) void k_initg(int* __restrict__ gcur, float* __restrict__ bins) {
    int t = threadIdx.x;
    if (t < NBKT) gcur[t] = t * CAPB;
    if (t < 64) bins[t] = 0.0f;
}

// ---------------------------------------------------------------------------
// k_bucket (round-10 verified): single-pass register staging. Each thread
// holds its EPT=4 edges (col,row) in registers from the ONE global read; the
// position pass reads registers. EPB 2048 -> LDS ~24.3KB -> 6 blocks/CU.
// Run-linear global writes (round-5 verified).
// ---------------------------------------------------------------------------
__global__ __launch_bounds__(512) void k_bucket(const int* __restrict__ row, const int* __restrict__ col,
                                                int* __restrict__ gcur, unsigned* __restrict__ csr) {
    __shared__ int hist[NBKT], gbase[NBKT], curi[NBKT], excl[NBKT];
    __shared__ int sc[512];
    __shared__ unsigned sdst[EPB];     // packed (d&255)<<17 | src, sorted by bucket
    __shared__ int sadr[EPB];          // final global csr address per slot
    int t = threadIdx.x;
    int e0 = blockIdx.x * EPB;
    int cnt = (N_EDGES - e0 < EPB) ? (N_EDGES - e0) : EPB;
    int dj[EPT], sj[EPT];
    bool vj[EPT];
    for (int k = t; k < NBKT; k += 512) hist[k] = 0;
#pragma unroll
    for (int i = 0; i < EPT; i++) {
        int j = t + i * 512;
        vj[i] = j < cnt;
        int jj = vj[i] ? j : 0;
        dj[i] = col[e0 + jj];
        sj[i] = row[e0 + jj];
    }
    __syncthreads();
#pragma unroll
    for (int i = 0; i < EPT; i++) if (vj[i]) atomicAdd(&hist[dj[i] >> 8], 1);
    __syncthreads();
    sc[t] = (t < NBKT) ? hist[t] : 0;
    __syncthreads();
    for (int off = 1; off < 512; off <<= 1) {
        int v = (t >= off) ? sc[t - off] : 0;
        __syncthreads();
        sc[t] += v;
        __syncthreads();
    }
    if (t < NBKT) {
        int e = sc[t] - hist[t];
        excl[t] = e;
        curi[t] = e;
        gbase[t] = (hist[t] > 0) ? atomicAdd(&gcur[t], hist[t]) : 0;
    }
    __syncthreads();
#pragma unroll
    for (int i = 0; i < EPT; i++) if (vj[i]) {
        int b = dj[i] >> 8;
        int pos = atomicAdd(&curi[b], 1);              // pos in [excl[b], excl[b]+hist[b])
        sdst[pos] = ((unsigned)(dj[i] & 255) << 17) | (unsigned)sj[i];
        sadr[pos] = gbase[b] + (pos - excl[b]);
    }
    __syncthreads();
    for (int j = t; j < cnt; j += 512) csr[sadr[j]] = sdst[j];   // run-linear writes
}

// ---------------------------------------------------------------------------
// k_sort: one block per bucket, 1024 threads; LDS counting sort (verified).
// ---------------------------------------------------------------------------
__global__ __launch_bounds__(1024) void k_sort(const int* __restrict__ gcur, unsigned* __restrict__ csr,
                                               int* __restrict__ rs, int* __restrict__ re,
                                               float* __restrict__ dinv) {
    __shared__ unsigned stage[CAPB];
    __shared__ int hist[256], offs[256], cur[256];
    int t = threadIdx.x, b = blockIdx.x;
    int base = b * CAPB;
    int cnt = gcur[b] - base;
    if (t < 256) hist[t] = 0;
    for (int j = t; j < cnt; j += 1024) stage[j] = csr[base + j];
    __syncthreads();
    for (int j = t; j < cnt; j += 1024) atomicAdd(&hist[stage[j] >> 17], 1);
    __syncthreads();
    if (t < 256) offs[t] = hist[t];
    __syncthreads();
    for (int off = 1; off < 256; off <<= 1) {
        int v = 0;
        if (t < 256 && t >= off) v = offs[t - off];
        __syncthreads();
        if (t < 256) offs[t] += v;
        __syncthreads();
    }
    if (t < 256) {
        int excl = offs[t] - hist[t];
        cur[t] = excl;
        int node = b * 256 + t;
        if (node < N_NODES) {
            rs[node] = base + excl;
            re[node] = base + excl + hist[t];
            dinv[node] = rsqrtf((float)(hist[t] + 1));   // +1 self loop
        }
    }
    __syncthreads();
    for (int j = t; j < cnt; j += 1024) {
        unsigned p = stage[j];
        int slot = atomicAdd(&cur[p >> 17], 1);
        csr[base + slot] = p & 0x1FFFFu;             // pure src
    }
}

// ---------------------------------------------------------------------------
// k_ab_h: bb = [x1 | tile(x2)] @ W4^T + b4  (float4 stores, f32)
//         h0 = dinv * (Wg @ [relu(x1@W1^T+b1) | bb])   (fp16 stores)
//         bins += W3[15:34].bb   (iteration-invariant output part)
// ---------------------------------------------------------------------------
__global__ __launch_bounds__(256) void k_ab_h(const float* __restrict__ x1, const float* __restrict__ x2,
                                              const float* __restrict__ W1, const float* __restrict__ b1,
                                              const float* __restrict__ W4, const float* __restrict__ b4,
                                              const float* __restrict__ Wg, const float* __restrict__ W3,
                                              const float* __restrict__ dinv,
                                              float* __restrict__ bb, __half* __restrict__ h0,
                                              float* __restrict__ bins) {
    __shared__ float sW1[225], sb1[15], sW4[361], sb4[19], sWg[510], sW3b[19];
    for (int t = threadIdx.x; t < 225; t += 256) sW1[t] = W1[t];
    for (int t = threadIdx.x; t < 361; t += 256) sW4[t] = W4[t];
    for (int t = threadIdx.x; t < 510; t += 256) sWg[t] = Wg[t];
    if (threadIdx.x < 15) sb1[threadIdx.x] = b1[threadIdx.x];
    if (threadIdx.x < 19) { sb4[threadIdx.x] = b4[threadIdx.x]; sW3b[threadIdx.x] = W3[15 + threadIdx.x]; }
    __syncthreads();
    int i = blockIdx.x * 256 + threadIdx.x;
    bool valid = i < N_NODES;
    int ii = valid ? i : 0;
    float x[15];
#pragma unroll
    for (int k = 0; k < 15; k++) x[k] = x1[(size_t)ii * 15 + k];
    float xt[4];
    int ib = ii % N_BASE;
#pragma unroll
    for (int k = 0; k < 4; k++) xt[k] = x2[(size_t)ib * 4 + k];
    float in[34];
    float bp = 0.0f;
#pragma unroll
    for (int o = 0; o < 19; o++) {
        float s = sb4[o];
#pragma unroll
        for (int k = 0; k < 15; k++) s += x[k] * sW4[o * 19 + k];
#pragma unroll
        for (int k = 0; k < 4; k++) s += xt[k] * sW4[o * 19 + 15 + k];
        in[15 + o] = s;
        bp += s * sW3b[o];
    }
#pragma unroll
    for (int o = 0; o < 15; o++) {
        float s = sb1[o];
#pragma unroll
        for (int k = 0; k < 15; k++) s += x[k] * sW1[o * 15 + k];
        in[o] = fmaxf(s, 0.0f);
    }
    float dn = dinv[ii];
    if (valid) {
        float4* bbp = (float4*)(bb + (size_t)ii * 20);
        bbp[0] = make_float4(in[15], in[16], in[17], in[18]);
        bbp[1] = make_float4(in[19], in[20], in[21], in[22]);
        bbp[2] = make_float4(in[23], in[24], in[25], in[26]);
        bbp[3] = make_float4(in[27], in[28], in[29], in[30]);
        bbp[4] = make_float4(in[31], in[32], in[33], 0.0f);   // [19] pad, never consumed
        float hv[15];
#pragma unroll
        for (int o = 0; o < 15; o++) {
            float s = 0.0f;
#pragma unroll
            for (int k = 0; k < 34; k++) s += in[k] * sWg[o * 34 + k];
            hv[o] = s * dn;
        }
        unsigned hu[8];
#pragma unroll
        for (int k = 0; k < 7; k++) hu[k] = pkh(hv[2 * k], hv[2 * k + 1]);
        hu[7] = pkh(hv[14], 0.0f);                            // ch 15 pad, always 0
        uint4* hp = (uint4*)(h0 + (size_t)ii * 16);
        hp[0] = make_uint4(hu[0], hu[1], hu[2], hu[3]);
        hp[1] = make_uint4(hu[4], hu[5], hu[6], hu[7]);
    }
    float val = valid ? bp : 0.0f;
#pragma unroll
    for (int off = 32; off > 0; off >>= 1) val += __shfl_down(val, off, 64);
    __shared__ float wsum[4];
    if ((threadIdx.x & 63) == 0) wsum[threadIdx.x >> 6] = val;
    __syncthreads();
    if (threadIdx.x == 0) atomicAdd(&bins[blockIdx.x & 63], wsum[0] + wsum[1] + wsum[2] + wsum[3]);
}

// ---------------------------------------------------------------------------
// k_gather (round-9-verified 1024-thread version, reverted from the round-10
// 256-thread experiment which regressed 42.4 -> 55.8 us: block size acts via
// per-block prologue amortization + intra-block csr locality, not occupancy).
// 64-edge batches with LANE-OWNED edges; lane serves node g = lane>>5, owns
// edges lg and lg+32, loads full 32B rows (2 x dwordx4, same 128B line).
// fp16 pk_add accumulation; per-lane reduce (send-the-discard-half); rev3
// source-lane epilogue.
// ---------------------------------------------------------------------------
__global__ __launch_bounds__(1024) void k_gather(const int* __restrict__ rs, const int* __restrict__ re,
                                                 const unsigned* __restrict__ csr,
                                                 const __half* __restrict__ h_in,
                                                 const float* __restrict__ dinv,
                                                 const float* __restrict__ bb,
                                                 const float* __restrict__ Wg,
                                                 const float* __restrict__ bg,
                                                 const float* __restrict__ W3,
                                                 __half* __restrict__ h_out,
                                                 float* __restrict__ bins, int last) {
    __shared__ float sWg[544], sbg[16], sW3[16];
    __shared__ float ws2[16];
    int t = threadIdx.x;
    for (int k = t; k < 544; k += 1024) sWg[k] = (k < 510) ? Wg[k] : 0.0f;
    if (t < 16) { sbg[t] = (t < 15) ? bg[t] : 0.0f; sW3[t] = (t < 15) ? W3[t] : 0.0f; }
    __syncthreads();
    int wid = t >> 6;
    int n0 = blockIdx.x * 32 + wid * 2;
    int lane = t & 63, g = lane >> 5, lg = lane & 31;
    int ng = n0 + g;
    int rsg = rs[ng];
    int degg = re[ng] - rsg;
    int dego = __shfl_xor(degg, 32, 64);
    int degm = degg > dego ? degg : dego;                  // wave-uniform bound
    const uint4* hp4 = (const uint4*)h_in;                 // one row = 2 uint4 (32B)
    // self row: full row on the lg==0 lane of each group (counted exactly once)
    uint4 sL = make_uint4(0u, 0u, 0u, 0u), sH = make_uint4(0u, 0u, 0u, 0u);
    if (lg == 0) { sL = hp4[(size_t)ng * 2]; sH = hp4[(size_t)ng * 2 + 1]; }
    unsigned a0 = sL.x, a1 = sL.y, a2 = sL.z, a3 = sL.w;
    unsigned a4 = sH.x, a5 = sH.y, a6 = sH.z, a7 = sH.w;
    for (int base = 0; base < degm; base += 64) {
        bool vA = base + lg < degg;
        bool vB = base + 32 + lg < degg;
        unsigned pa = 0u, pb = 0u;
        if (vA) pa = csr[rsg + base + lg];
        if (vB) pb = csr[rsg + base + 32 + lg];
        uint4 vaL = make_uint4(0u, 0u, 0u, 0u), vaH = make_uint4(0u, 0u, 0u, 0u);
        uint4 vbL = make_uint4(0u, 0u, 0u, 0u), vbH = make_uint4(0u, 0u, 0u, 0u);
        if (vA) { vaL = hp4[(size_t)pa * 2]; vaH = hp4[(size_t)pa * 2 + 1]; }
        if (vB) { vbL = hp4[(size_t)pb * 2]; vbH = hp4[(size_t)pb * 2 + 1]; }
        a0 = hadd2u(a0, vaL.x); a1 = hadd2u(a1, vaL.y);
        a2 = hadd2u(a2, vaL.z); a3 = hadd2u(a3, vaL.w);
        a4 = hadd2u(a4, vaH.x); a5 = hadd2u(a5, vaH.y);
        a6 = hadd2u(a6, vaH.z); a7 = hadd2u(a7, vaH.w);
        a0 = hadd2u(a0, vbL.x); a1 = hadd2u(a1, vbL.y);
        a2 = hadd2u(a2, vbL.z); a3 = hadd2u(a3, vbL.w);
        a4 = hadd2u(a4, vbH.x); a5 = hadd2u(a5, vbH.y);
        a6 = hadd2u(a6, vbH.z); a7 = hadd2u(a7, vbH.w);
    }
    // per-lane reduce over lg bits 0..4 (send-the-discard-half); lane ends
    // holding row dword pr = 4*b0 + 2*b1 + b2 of its node's sum.
    int b0 = lg & 1, b1 = (lg >> 1) & 1, b2 = (lg >> 2) & 1;
    unsigned kA0 = b0 ? a4 : a0, kA1 = b0 ? a5 : a1, kA2 = b0 ? a6 : a2, kA3 = b0 ? a7 : a3;
    unsigned sA0 = b0 ? a0 : a4, sA1 = b0 ? a1 : a5, sA2 = b0 ? a2 : a6, sA3 = b0 ? a3 : a7;
    kA0 = hadd2u(kA0, __shfl_xor(sA0, 1, 64));
    kA1 = hadd2u(kA1, __shfl_xor(sA1, 1, 64));
    kA2 = hadd2u(kA2, __shfl_xor(sA2, 1, 64));
    kA3 = hadd2u(kA3, __shfl_xor(sA3, 1, 64));
    unsigned kB0 = b1 ? kA2 : kA0, kB1 = b1 ? kA3 : kA1;
    unsigned sB0 = b1 ? kA0 : kA2, sB1 = b1 ? kA1 : kA3;
    kB0 = hadd2u(kB0, __shfl_xor(sB0, 2, 64));
    kB1 = hadd2u(kB1, __shfl_xor(sB1, 2, 64));
    unsigned kk = b2 ? kB1 : kB0;
    unsigned sd = b2 ? kB0 : kB1;
    kk = hadd2u(kk, __shfl_xor(sd, 4, 64));
    kk = hadd2u(kk, __shfl_xor(kk, 8, 64));
    kk = hadd2u(kk, __shfl_xor(kk, 16, 64));
    int pr = 4 * b0 + 2 * b1 + b2;
    float dng = dinv[ng];
    float2 f = __half22float2(*(__half2*)&kk);
    float avx = fmaxf(dng * f.x + sbg[2 * pr], 0.0f);
    float avy = fmaxf(dng * f.y + sbg[2 * pr + 1], 0.0f);   // pr==7 -> ch15 = 0
    if (!last) {
        int n1 = n0 + 1;
        float dn0 = __shfl(dng, 0, 64), dn1 = __shfl(dng, 32, 64);
        int p = lane >> 3, c2e = lane & 7, o0 = 2 * c2e;
        // pair j of node g lives on lane 32*g + rev3(j)
        int j0 = p >> 1, j1 = (p + 8) >> 1;
        int l0 = ((j0 & 1) << 2) | (j0 & 2) | ((j0 >> 2) & 1);
        int l1 = ((j1 & 1) << 2) | (j1 & 2) | ((j1 >> 2) & 1);
        float ex0a = __shfl(avx, l0, 64),      ey0a = __shfl(avy, l0, 64);
        float ex1a = __shfl(avx, l1, 64),      ey1a = __shfl(avy, l1, 64);
        float ex0b = __shfl(avx, 32 + l0, 64), ey0b = __shfl(avy, 32 + l0, 64);
        float ex1b = __shfl(avx, 32 + l1, 64), ey1b = __shfl(avy, 32 + l1, 64);
        float inv0a = (p & 1) ? ey0a : ex0a;
        float inv1a = (p & 1) ? ey1a : ex1a;
        float inv0b = (p & 1) ? ey0b : ex0b;
        float inv1b = (p & 1) ? ey1b : ex1b;
        if (p == 7) { inv1a = bb[(size_t)n0 * 20 + 0]; inv1b = bb[(size_t)n1 * 20 + 0]; }
        float wq0 = sWg[o0 * 34 + p],       wq1 = sWg[o0 * 34 + p + 8];
        float wr0 = sWg[(o0 + 1) * 34 + p], wr1 = sWg[(o0 + 1) * 34 + p + 8];
        float s0a = inv0a * wq0 + inv1a * wq1;
        float s1a = inv0a * wr0 + inv1a * wr1;
        float s0b = inv0b * wq0 + inv1b * wq1;
        float s1b = inv0b * wr0 + inv1b * wr1;
#pragma unroll
        for (int i = 2; i < 5; i++) {
            int k = p + 8 * i;
            if (k < 34) {
                float ia = bb[(size_t)n0 * 20 + (k - 15)];
                float ib2 = bb[(size_t)n1 * 20 + (k - 15)];
                float w0 = sWg[o0 * 34 + k], w1 = sWg[(o0 + 1) * 34 + k];
                s0a += ia * w0; s1a += ia * w1;
                s0b += ib2 * w0; s1b += ib2 * w1;
            }
        }
        s0a += __shfl_xor(s0a, 8, 64);  s1a += __shfl_xor(s1a, 8, 64);
        s0a += __shfl_xor(s0a, 16, 64); s1a += __shfl_xor(s1a, 16, 64);
        s0a += __shfl_xor(s0a, 32, 64); s1a += __shfl_xor(s1a, 32, 64);
        s0b += __shfl_xor(s0b, 8, 64);  s1b += __shfl_xor(s1b, 8, 64);
        s0b += __shfl_xor(s0b, 16, 64); s1b += __shfl_xor(s1b, 16, 64);
        s0b += __shfl_xor(s0b, 32, 64); s1b += __shfl_xor(s1b, 32, 64);
        if (p == 0) {
            ((unsigned*)h_out)[(size_t)n0 * 8 + c2e] = pkh(s0a * dn0, s1a * dn0);
            ((unsigned*)h_out)[(size_t)n1 * 8 + c2e] = pkh(s0b * dn1, s1b * dn1);
        }
    } else {
        float c = 0.0f;
        if (lg < 8) c = avx * sW3[2 * pr] + avy * sW3[2 * pr + 1];   // sW3[15]==0
        c += __shfl_xor(c, 1, 64);
        c += __shfl_xor(c, 2, 64);
        c += __shfl_xor(c, 4, 64);        // lane0 = node0 sum, lane32 = node1 sum
        c += __shfl_xor(c, 32, 64);       // combine groups
        if (lane == 0) ws2[wid] = c;
        __syncthreads();
        if (t == 0) {
            float s = 0.0f;
#pragma unroll
            for (int k = 0; k < 16; k++) s += ws2[k];
            atomicAdd(&bins[blockIdx.x & 63], s);
        }
    }
}

__global__ void k_finalize(const float* __restrict__ bins, const float* __restrict__ b3,
                           float* __restrict__ out) {
    float s = 0.0f;
    for (int k = 0; k < 64; k++) s += bins[k];
    out[0] = tanhf(s * (1.0f / (float)N_NODES) + b3[0]);
}

// ---------------------------------------------------------------------------
extern "C" void kernel_launch(void* const* d_in, const int* in_sizes, int n_in,
                              void* d_out, int out_size, void* d_ws, size_t ws_size,
                              hipStream_t stream) {
    const float* x1 = (const float*)d_in[0];
    const float* x2 = (const float*)d_in[1];
    const int* edges = (const int*)d_in[2];
    const float* W1 = (const float*)d_in[3];
    const float* b1 = (const float*)d_in[4];
    const float* Wg = (const float*)d_in[5];
    const float* bg = (const float*)d_in[6];
    const float* W3 = (const float*)d_in[7];
    const float* b3 = (const float*)d_in[8];
    const float* W4 = (const float*)d_in[9];
    const float* b4 = (const float*)d_in[10];

    const int* row = edges;             // edges[0]
    const int* col = edges + N_EDGES;   // edges[1]

    // workspace layout — ~30 MB (h0/h1 fp16: 3.2 MB each).
    char* ws = (char*)d_ws;
    unsigned* csr  = (unsigned*)ws;                              // NBKT*CAPB  (14.81 MB)
    float*    bb   = (float*)(csr + (size_t)NBKT * CAPB);        // N*20 f32   (8.0 MB)
    __half*   h0   = (__half*)(bb + (size_t)N_NODES * 20);       // N*16 fp16  (3.2 MB)
    __half*   h1   = h0 + (size_t)N_NODES * 16;                  // N*16 fp16  (3.2 MB)
    float*    dinv = (float*)(h1 + (size_t)N_NODES * 16);        // N
    int*      rs   = (int*)(dinv + N_NODES);                     // N
    int*      re   = rs + N_NODES;                               // N
    int*      gcur = re + N_NODES;                               // NBKT
    float*    bins = (float*)(gcur + NBKT);                      // 64

    int gN = (N_NODES + 255) / 256;                              // 391

    k_initg<<<1, 512, 0, stream>>>(gcur, bins);
    k_bucket<<<GEB, 512, 0, stream>>>(row, col, gcur, csr);
    k_sort<<<NBKT, 1024, 0, stream>>>(gcur, csr, rs, re, dinv);
    k_ab_h<<<gN, 256, 0, stream>>>(x1, x2, W1, b1, W4, b4, Wg, W3, dinv, bb, h0, bins);
    for (int t = 0; t < 5; t++) {
        const __half* hi = (t & 1) ? h1 : h0;
        __half* ho = (t & 1) ? h0 : h1;
        k_gather<<<N_NODES / 32, 1024, 0, stream>>>(rs, re, csr, hi, dinv, bb, Wg, bg, W3,
                                                    ho, bins, t == 4 ? 1 : 0);
    }
    k_finalize<<<1, 1, 0, stream>>>(bins, b3, (float*)d_out);
}

// Round 12
// 334.447 us; speedup vs baseline: 1.0887x; 1.0492x over previous
//
#include <hip/hip_runtime.h>
#include <hip/hip_fp16.h>
#include <math.h>

#define N_NODES 100000
#define N_BASE  5000
#define N_EDGES 3200000
#define NBKT    391       // dest buckets of 256 nodes
#define CAPB    9472      // csr slots per bucket (mean 8184, sigma 90 -> +14 sigma)
#define EPB     4096      // edges per k_bucket block (round-9 config)
#define GEB     782       // ceil(N_EDGES / EPB)

typedef float f32x2 __attribute__((ext_vector_type(2)));

// unpack 16 fp8(e4m3) bytes and accumulate into 16 f32 channels
__device__ inline void acc16(uint4 v, float* c) {
    f32x2 p;
    p = __builtin_amdgcn_cvt_pk_f32_fp8((int)v.x, false); c[0] += p.x;  c[1] += p.y;
    p = __builtin_amdgcn_cvt_pk_f32_fp8((int)v.x, true ); c[2] += p.x;  c[3] += p.y;
    p = __builtin_amdgcn_cvt_pk_f32_fp8((int)v.y, false); c[4] += p.x;  c[5] += p.y;
    p = __builtin_amdgcn_cvt_pk_f32_fp8((int)v.y, true ); c[6] += p.x;  c[7] += p.y;
    p = __builtin_amdgcn_cvt_pk_f32_fp8((int)v.z, false); c[8] += p.x;  c[9] += p.y;
    p = __builtin_amdgcn_cvt_pk_f32_fp8((int)v.z, true ); c[10] += p.x; c[11] += p.y;
    p = __builtin_amdgcn_cvt_pk_f32_fp8((int)v.w, false); c[12] += p.x; c[13] += p.y;
    p = __builtin_amdgcn_cvt_pk_f32_fp8((int)v.w, true ); c[14] += p.x; c[15] += p.y;
}

// ---------------------------------------------------------------------------
// k_initg: gcur[b] = b*CAPB, bins = 0
// ---------------------------------------------------------------------------
__global__ __launch_bounds__(512) void k_initg(int* __restrict__ gcur, float* __restrict__ bins) {
    int t = threadIdx.x;
    if (t < NBKT) gcur[t] = t * CAPB;
    if (t < 64) bins[t] = 0.0f;
}

// ---------------------------------------------------------------------------
// k_bucket (round-9 config, best measured total): 782 blocks x 4096 edges x
// 512 threads; LDS position-sort then run-linear global writes.
// ---------------------------------------------------------------------------
__global__ __launch_bounds__(512) void k_bucket(const int* __restrict__ row, const int* __restrict__ col,
                                                int* __restrict__ gcur, unsigned* __restrict__ csr) {
    __shared__ int hist[NBKT], gbase[NBKT], curi[NBKT], excl[NBKT];
    __shared__ int sc[512];
    __shared__ unsigned sdst[EPB];     // packed (d&255)<<17 | src, sorted by bucket
    __shared__ int sadr[EPB];          // final global csr address per slot
    int t = threadIdx.x;
    int e0 = blockIdx.x * EPB;
    int cnt = (N_EDGES - e0 < EPB) ? (N_EDGES - e0) : EPB;
    for (int k = t; k < NBKT; k += 512) hist[k] = 0;
    __syncthreads();
    for (int j = t; j < cnt; j += 512) atomicAdd(&hist[col[e0 + j] >> 8], 1);
    __syncthreads();
    sc[t] = (t < NBKT) ? hist[t] : 0;
    __syncthreads();
    for (int off = 1; off < 512; off <<= 1) {
        int v = (t >= off) ? sc[t - off] : 0;
        __syncthreads();
        sc[t] += v;
        __syncthreads();
    }
    if (t < NBKT) {
        int e = sc[t] - hist[t];
        excl[t] = e;
        curi[t] = e;
        gbase[t] = (hist[t] > 0) ? atomicAdd(&gcur[t], hist[t]) : 0;
    }
    __syncthreads();
    for (int j = t; j < cnt; j += 512) {
        int d = col[e0 + j];           // L2-warm re-read
        int s = row[e0 + j];
        int b = d >> 8;
        int pos = atomicAdd(&curi[b], 1);              // pos in [excl[b], excl[b]+hist[b])
        sdst[pos] = ((unsigned)(d & 255) << 17) | (unsigned)s;
        sadr[pos] = gbase[b] + (pos - excl[b]);
    }
    __syncthreads();
    for (int j = t; j < cnt; j += 512) csr[sadr[j]] = sdst[j];   // run-linear writes
}

// ---------------------------------------------------------------------------
// k_sort: one block per bucket, 1024 threads; LDS counting sort (verified).
// ---------------------------------------------------------------------------
__global__ __launch_bounds__(1024) void k_sort(const int* __restrict__ gcur, unsigned* __restrict__ csr,
                                               int* __restrict__ rs, int* __restrict__ re,
                                               float* __restrict__ dinv) {
    __shared__ unsigned stage[CAPB];
    __shared__ int hist[256], offs[256], cur[256];
    int t = threadIdx.x, b = blockIdx.x;
    int base = b * CAPB;
    int cnt = gcur[b] - base;
    if (t < 256) hist[t] = 0;
    for (int j = t; j < cnt; j += 1024) stage[j] = csr[base + j];
    __syncthreads();
    for (int j = t; j < cnt; j += 1024) atomicAdd(&hist[stage[j] >> 17], 1);
    __syncthreads();
    if (t < 256) offs[t] = hist[t];
    __syncthreads();
    for (int off = 1; off < 256; off <<= 1) {
        int v = 0;
        if (t < 256 && t >= off) v = offs[t - off];
        __syncthreads();
        if (t < 256) offs[t] += v;
        __syncthreads();
    }
    if (t < 256) {
        int excl = offs[t] - hist[t];
        cur[t] = excl;
        int node = b * 256 + t;
        if (node < N_NODES) {
            rs[node] = base + excl;
            re[node] = base + excl + hist[t];
            dinv[node] = rsqrtf((float)(hist[t] + 1));   // +1 self loop
        }
    }
    __syncthreads();
    for (int j = t; j < cnt; j += 1024) {
        unsigned p = stage[j];
        int slot = atomicAdd(&cur[p >> 17], 1);
        csr[base + slot] = p & 0x1FFFFu;             // pure src
    }
}

// ---------------------------------------------------------------------------
// k_ab_h: bb = [x1 | tile(x2)] @ W4^T + b4  (float4 stores, f32)
//         h0 = dinv * (Wg @ [relu(x1@W1^T+b1) | bb])   ** fp8 e4m3 stores **
//         bins += W3[15:34].bb   (iteration-invariant output part)
// h rows are now 16 fp8 bytes (ch 0..14 + pad): ONE dwordx4 per gather.
// ---------------------------------------------------------------------------
__global__ __launch_bounds__(256) void k_ab_h(const float* __restrict__ x1, const float* __restrict__ x2,
                                              const float* __restrict__ W1, const float* __restrict__ b1,
                                              const float* __restrict__ W4, const float* __restrict__ b4,
                                              const float* __restrict__ Wg, const float* __restrict__ W3,
                                              const float* __restrict__ dinv,
                                              float* __restrict__ bb, unsigned* __restrict__ h0,
                                              float* __restrict__ bins) {
    __shared__ float sW1[225], sb1[15], sW4[361], sb4[19], sWg[510], sW3b[19];
    for (int t = threadIdx.x; t < 225; t += 256) sW1[t] = W1[t];
    for (int t = threadIdx.x; t < 361; t += 256) sW4[t] = W4[t];
    for (int t = threadIdx.x; t < 510; t += 256) sWg[t] = Wg[t];
    if (threadIdx.x < 15) sb1[threadIdx.x] = b1[threadIdx.x];
    if (threadIdx.x < 19) { sb4[threadIdx.x] = b4[threadIdx.x]; sW3b[threadIdx.x] = W3[15 + threadIdx.x]; }
    __syncthreads();
    int i = blockIdx.x * 256 + threadIdx.x;
    bool valid = i < N_NODES;
    int ii = valid ? i : 0;
    float x[15];
#pragma unroll
    for (int k = 0; k < 15; k++) x[k] = x1[(size_t)ii * 15 + k];
    float xt[4];
    int ib = ii % N_BASE;
#pragma unroll
    for (int k = 0; k < 4; k++) xt[k] = x2[(size_t)ib * 4 + k];
    float in[34];
    float bp = 0.0f;
#pragma unroll
    for (int o = 0; o < 19; o++) {
        float s = sb4[o];
#pragma unroll
        for (int k = 0; k < 15; k++) s += x[k] * sW4[o * 19 + k];
#pragma unroll
        for (int k = 0; k < 4; k++) s += xt[k] * sW4[o * 19 + 15 + k];
        in[15 + o] = s;
        bp += s * sW3b[o];
    }
#pragma unroll
    for (int o = 0; o < 15; o++) {
        float s = sb1[o];
#pragma unroll
        for (int k = 0; k < 15; k++) s += x[k] * sW1[o * 15 + k];
        in[o] = fmaxf(s, 0.0f);
    }
    float dn = dinv[ii];
    if (valid) {
        float4* bbp = (float4*)(bb + (size_t)ii * 20);
        bbp[0] = make_float4(in[15], in[16], in[17], in[18]);
        bbp[1] = make_float4(in[19], in[20], in[21], in[22]);
        bbp[2] = make_float4(in[23], in[24], in[25], in[26]);
        bbp[3] = make_float4(in[27], in[28], in[29], in[30]);
        bbp[4] = make_float4(in[31], in[32], in[33], 0.0f);   // [19] pad, never consumed
        float hvv[16];
#pragma unroll
        for (int o = 0; o < 15; o++) {
            float s = 0.0f;
#pragma unroll
            for (int k = 0; k < 34; k++) s += in[k] * sWg[o * 34 + k];
            hvv[o] = s * dn;
        }
        hvv[15] = 0.0f;                                       // ch 15 pad, always 0
        unsigned hu[4];
#pragma unroll
        for (int q2 = 0; q2 < 4; q2++) {
            int v = 0;
            v = __builtin_amdgcn_cvt_pk_fp8_f32(hvv[4 * q2],     hvv[4 * q2 + 1], v, false);
            v = __builtin_amdgcn_cvt_pk_fp8_f32(hvv[4 * q2 + 2], hvv[4 * q2 + 3], v, true);
            hu[q2] = (unsigned)v;
        }
        *(uint4*)(h0 + (size_t)ii * 4) = make_uint4(hu[0], hu[1], hu[2], hu[3]);
    }
    float val = valid ? bp : 0.0f;
#pragma unroll
    for (int off = 32; off > 0; off >>= 1) val += __shfl_down(val, off, 64);
    __shared__ float wsum[4];
    if ((threadIdx.x & 63) == 0) wsum[threadIdx.x >> 6] = val;
    __syncthreads();
    if (threadIdx.x == 0) atomicAdd(&bins[blockIdx.x & 63], wsum[0] + wsum[1] + wsum[2] + wsum[3]);
}

// ---------------------------------------------------------------------------
// k_gather (round 12): round-9 structure (verified best) with fp8 h rows.
// Each lane owns edges lg, lg+32 of node g = lane>>5 and loads the FULL row
// as ONE dwordx4 (16 fp8 bytes) -- random 16B L2 requests per dispatch halve
// (6.4M -> 3.2M) and the h working set drops to 1.6MB. Accumulation is now
// f32 (16 regs, BETTER precision than the previous fp16 accumulate; only
// fp8 storage quantization is new). Reduce: same send-the-discard-half tree
// over lg bits 0..4 on 8 float pairs (18 shfl); lane ends with channel pair
// pr = 4*b0+2*b1+b2 -- identical pr/rev3 mapping to the verified r9 epilogue.
// h_out: lanes pack 2 channels to fp8 u16, even lanes combine with neighbor
// via one shfl and store dwords (no sub-dword stores).
// ---------------------------------------------------------------------------
__global__ __launch_bounds__(1024) void k_gather(const int* __restrict__ rs, const int* __restrict__ re,
                                                 const unsigned* __restrict__ csr,
                                                 const uint4* __restrict__ h_in,
                                                 const float* __restrict__ dinv,
                                                 const float* __restrict__ bb,
                                                 const float* __restrict__ Wg,
                                                 const float* __restrict__ bg,
                                                 const float* __restrict__ W3,
                                                 unsigned* __restrict__ h_out,
                                                 float* __restrict__ bins, int last) {
    __shared__ float sWg[544], sbg[16], sW3[16];
    __shared__ float ws2[16];
    int t = threadIdx.x;
    for (int k = t; k < 544; k += 1024) sWg[k] = (k < 510) ? Wg[k] : 0.0f;
    if (t < 16) { sbg[t] = (t < 15) ? bg[t] : 0.0f; sW3[t] = (t < 15) ? W3[t] : 0.0f; }
    __syncthreads();
    int wid = t >> 6;
    int n0 = blockIdx.x * 32 + wid * 2;
    int lane = t & 63, g = lane >> 5, lg = lane & 31;
    int ng = n0 + g;
    int rsg = rs[ng];
    int degg = re[ng] - rsg;
    int dego = __shfl_xor(degg, 32, 64);
    int degm = degg > dego ? degg : dego;                  // wave-uniform bound
    float c[16];
#pragma unroll
    for (int j = 0; j < 16; j++) c[j] = 0.0f;
    // self row: on the lg==0 lane of each group (counted exactly once)
    if (lg == 0) { uint4 sv = h_in[ng]; acc16(sv, c); }
    for (int base = 0; base < degm; base += 64) {
        bool vA = base + lg < degg;
        bool vB = base + 32 + lg < degg;
        unsigned pa = 0u, pb = 0u;
        if (vA) pa = csr[rsg + base + lg];
        if (vB) pb = csr[rsg + base + 32 + lg];
        uint4 va = make_uint4(0u, 0u, 0u, 0u), vb = make_uint4(0u, 0u, 0u, 0u);
        if (vA) va = h_in[pa];
        if (vB) vb = h_in[pb];
        acc16(va, c);
        acc16(vb, c);
    }
    // reduce over lg bits 0..4 (send-the-discard-half) on 8 float pairs;
    // lane ends holding channel pair pr = 4*b0 + 2*b1 + b2 of its node.
    int b0 = lg & 1, b1 = (lg >> 1) & 1, b2 = (lg >> 2) & 1;
    float kA0 = b0 ? c[8]  : c[0],  sA0 = b0 ? c[0] : c[8];
    float kA1 = b0 ? c[9]  : c[1],  sA1 = b0 ? c[1] : c[9];
    float kA2 = b0 ? c[10] : c[2],  sA2 = b0 ? c[2] : c[10];
    float kA3 = b0 ? c[11] : c[3],  sA3 = b0 ? c[3] : c[11];
    float kA4 = b0 ? c[12] : c[4],  sA4 = b0 ? c[4] : c[12];
    float kA5 = b0 ? c[13] : c[5],  sA5 = b0 ? c[5] : c[13];
    float kA6 = b0 ? c[14] : c[6],  sA6 = b0 ? c[6] : c[14];
    float kA7 = b0 ? c[15] : c[7],  sA7 = b0 ? c[7] : c[15];
    kA0 += __shfl_xor(sA0, 1, 64);
    kA1 += __shfl_xor(sA1, 1, 64);
    kA2 += __shfl_xor(sA2, 1, 64);
    kA3 += __shfl_xor(sA3, 1, 64);
    kA4 += __shfl_xor(sA4, 1, 64);
    kA5 += __shfl_xor(sA5, 1, 64);
    kA6 += __shfl_xor(sA6, 1, 64);
    kA7 += __shfl_xor(sA7, 1, 64);
    float kB0 = b1 ? kA4 : kA0, sB0 = b1 ? kA0 : kA4;
    float kB1 = b1 ? kA5 : kA1, sB1 = b1 ? kA1 : kA5;
    float kB2 = b1 ? kA6 : kA2, sB2 = b1 ? kA2 : kA6;
    float kB3 = b1 ? kA7 : kA3, sB3 = b1 ? kA3 : kA7;
    kB0 += __shfl_xor(sB0, 2, 64);
    kB1 += __shfl_xor(sB1, 2, 64);
    kB2 += __shfl_xor(sB2, 2, 64);
    kB3 += __shfl_xor(sB3, 2, 64);
    float kk0 = b2 ? kB2 : kB0, sd0 = b2 ? kB0 : kB2;
    float kk1 = b2 ? kB3 : kB1, sd1 = b2 ? kB1 : kB3;
    kk0 += __shfl_xor(sd0, 4, 64);
    kk1 += __shfl_xor(sd1, 4, 64);
    kk0 += __shfl_xor(kk0, 8, 64);
    kk1 += __shfl_xor(kk1, 8, 64);
    kk0 += __shfl_xor(kk0, 16, 64);
    kk1 += __shfl_xor(kk1, 16, 64);
    int pr = 4 * b0 + 2 * b1 + b2;
    float dng = dinv[ng];
    float avx = fmaxf(dng * kk0 + sbg[2 * pr], 0.0f);
    float avy = fmaxf(dng * kk1 + sbg[2 * pr + 1], 0.0f);   // pr==7 -> ch15 = 0
    if (!last) {
        int n1 = n0 + 1;
        float dn0 = __shfl(dng, 0, 64), dn1 = __shfl(dng, 32, 64);
        int p = lane >> 3, c2e = lane & 7, o0 = 2 * c2e;
        // pair j of node g lives on lane 32*g + rev3(j)
        int j0 = p >> 1, j1 = (p + 8) >> 1;
        int l0 = ((j0 & 1) << 2) | (j0 & 2) | ((j0 >> 2) & 1);
        int l1 = ((j1 & 1) << 2) | (j1 & 2) | ((j1 >> 2) & 1);
        float ex0a = __shfl(avx, l0, 64),      ey0a = __shfl(avy, l0, 64);
        float ex1a = __shfl(avx, l1, 64),      ey1a = __shfl(avy, l1, 64);
        float ex0b = __shfl(avx, 32 + l0, 64), ey0b = __shfl(avy, 32 + l0, 64);
        float ex1b = __shfl(avx, 32 + l1, 64), ey1b = __shfl(avy, 32 + l1, 64);
        float inv0a = (p & 1) ? ey0a : ex0a;
        float inv1a = (p & 1) ? ey1a : ex1a;
        float inv0b = (p & 1) ? ey0b : ex0b;
        float inv1b = (p & 1) ? ey1b : ex1b;
        if (p == 7) { inv1a = bb[(size_t)n0 * 20 + 0]; inv1b = bb[(size_t)n1 * 20 + 0]; }
        float wq0 = sWg[o0 * 34 + p],       wq1 = sWg[o0 * 34 + p + 8];
        float wr0 = sWg[(o0 + 1) * 34 + p], wr1 = sWg[(o0 + 1) * 34 + p + 8];
        float s0a = inv0a * wq0 + inv1a * wq1;
        float s1a = inv0a * wr0 + inv1a * wr1;
        float s0b = inv0b * wq0 + inv1b * wq1;
        float s1b = inv0b * wr0 + inv1b * wr1;
#pragma unroll
        for (int i = 2; i < 5; i++) {
            int k = p + 8 * i;
            if (k < 34) {
                float ia = bb[(size_t)n0 * 20 + (k - 15)];
                float ib2 = bb[(size_t)n1 * 20 + (k - 15)];
                float w0 = sWg[o0 * 34 + k], w1 = sWg[(o0 + 1) * 34 + k];
                s0a += ia * w0; s1a += ia * w1;
                s0b += ib2 * w0; s1b += ib2 * w1;
            }
        }
        s0a += __shfl_xor(s0a, 8, 64);  s1a += __shfl_xor(s1a, 8, 64);
        s0a += __shfl_xor(s0a, 16, 64); s1a += __shfl_xor(s1a, 16, 64);
        s0a += __shfl_xor(s0a, 32, 64); s1a += __shfl_xor(s1a, 32, 64);
        s0b += __shfl_xor(s0b, 8, 64);  s1b += __shfl_xor(s1b, 8, 64);
        s0b += __shfl_xor(s0b, 16, 64); s1b += __shfl_xor(s1b, 16, 64);
        s0b += __shfl_xor(s0b, 32, 64); s1b += __shfl_xor(s1b, 32, 64);
        // fp8 pack: lane c2e holds channels 2c2e,2c2e+1 for n0 (and n1);
        // even lanes combine with neighbor (c2e^1) and store one dword.
        int ua = __builtin_amdgcn_cvt_pk_fp8_f32(s0a * dn0, s1a * dn0, 0, false);
        int ub = __builtin_amdgcn_cvt_pk_fp8_f32(s0b * dn1, s1b * dn1, 0, false);
        unsigned nba = ((unsigned)__shfl(ua, lane ^ 1, 64)) & 0xFFFFu;
        unsigned nbb = ((unsigned)__shfl(ub, lane ^ 1, 64)) & 0xFFFFu;
        if (p == 0 && (c2e & 1) == 0) {
            h_out[(size_t)n0 * 4 + (c2e >> 1)] = (((unsigned)ua) & 0xFFFFu) | (nba << 16);
            h_out[(size_t)n1 * 4 + (c2e >> 1)] = (((unsigned)ub) & 0xFFFFu) | (nbb << 16);
        }
    } else {
        float cc = 0.0f;
        if (lg < 8) cc = avx * sW3[2 * pr] + avy * sW3[2 * pr + 1];   // sW3[15]==0
        cc += __shfl_xor(cc, 1, 64);
        cc += __shfl_xor(cc, 2, 64);
        cc += __shfl_xor(cc, 4, 64);      // lane0 = node0 sum, lane32 = node1 sum
        cc += __shfl_xor(cc, 32, 64);     // combine groups
        if (lane == 0) ws2[wid] = cc;
        __syncthreads();
        if (t == 0) {
            float s = 0.0f;
#pragma unroll
            for (int k = 0; k < 16; k++) s += ws2[k];
            atomicAdd(&bins[blockIdx.x & 63], s);
        }
    }
}

__global__ void k_finalize(const float* __restrict__ bins, const float* __restrict__ b3,
                           float* __restrict__ out) {
    float s = 0.0f;
    for (int k = 0; k < 64; k++) s += bins[k];
    out[0] = tanhf(s * (1.0f / (float)N_NODES) + b3[0]);
}

// ---------------------------------------------------------------------------
extern "C" void kernel_launch(void* const* d_in, const int* in_sizes, int n_in,
                              void* d_out, int out_size, void* d_ws, size_t ws_size,
                              hipStream_t stream) {
    const float* x1 = (const float*)d_in[0];
    const float* x2 = (const float*)d_in[1];
    const int* edges = (const int*)d_in[2];
    const float* W1 = (const float*)d_in[3];
    const float* b1 = (const float*)d_in[4];
    const float* Wg = (const float*)d_in[5];
    const float* bg = (const float*)d_in[6];
    const float* W3 = (const float*)d_in[7];
    const float* b3 = (const float*)d_in[8];
    const float* W4 = (const float*)d_in[9];
    const float* b4 = (const float*)d_in[10];

    const int* row = edges;             // edges[0]
    const int* col = edges + N_EDGES;   // edges[1]

    // workspace layout — ~26 MB (h0/h1 fp8: 1.6 MB each).
    char* ws = (char*)d_ws;
    unsigned* csr  = (unsigned*)ws;                              // NBKT*CAPB  (14.81 MB)
    float*    bb   = (float*)(csr + (size_t)NBKT * CAPB);        // N*20 f32   (8.0 MB)
    unsigned* h0   = (unsigned*)(bb + (size_t)N_NODES * 20);     // N*4 u32    (1.6 MB, fp8 rows)
    unsigned* h1   = h0 + (size_t)N_NODES * 4;                   // N*4 u32    (1.6 MB)
    float*    dinv = (float*)(h1 + (size_t)N_NODES * 4);         // N
    int*      rs   = (int*)(dinv + N_NODES);                     // N
    int*      re   = rs + N_NODES;                               // N
    int*      gcur = re + N_NODES;                               // NBKT
    float*    bins = (float*)(gcur + NBKT);                      // 64

    int gN = (N_NODES + 255) / 256;                              // 391

    k_initg<<<1, 512, 0, stream>>>(gcur, bins);
    k_bucket<<<GEB, 512, 0, stream>>>(row, col, gcur, csr);
    k_sort<<<NBKT, 1024, 0, stream>>>(gcur, csr, rs, re, dinv);
    k_ab_h<<<gN, 256, 0, stream>>>(x1, x2, W1, b1, W4, b4, Wg, W3, dinv, bb, h0, bins);
    for (int t = 0; t < 5; t++) {
        const unsigned* hi = (t & 1) ? h1 : h0;
        unsigned* ho = (t & 1) ? h0 : h1;
        k_gather<<<N_NODES / 32, 1024, 0, stream>>>(rs, re, csr, (const uint4*)hi, dinv, bb,
                                                    Wg, bg, W3, ho, bins, t == 4 ? 1 : 0);
    }
    k_finalize<<<1, 1, 0, stream>>>(bins, b3, (float*)d_out);
}